// Round 1
// baseline (734.554 us; speedup 1.0000x reference)
//
#include <hip/hip_runtime.h>
#include <math.h>

#define BB 4
#define CC 64
#define PP 4096
#define CI 16

// ---------------------------------------------------------------------------
// Kernel 1: q/k/v projections.
// grid = B * (P/64) = 256 blocks, 256 threads.
// q stored [B,P,CI], k stored [B,CI,P], v stored [B,C,P].
// ---------------------------------------------------------------------------
__global__ __launch_bounds__(256) void qkv_kernel(
    const float* __restrict__ ftr, const float* __restrict__ wq, const float* __restrict__ bq,
    const float* __restrict__ wk, const float* __restrict__ bk,
    const float* __restrict__ wv, const float* __restrict__ bv,
    float* __restrict__ q_out, float* __restrict__ k_out, float* __restrict__ v_out)
{
    __shared__ float xs[64][65];   // x[b, c, p0+j], padded
    __shared__ float wqs[16][64];
    __shared__ float wks[16][64];
    __shared__ float wvs[64][64];

    int b  = blockIdx.x >> 6;
    int p0 = (blockIdx.x & 63) << 6;
    int tid = threadIdx.x;

    for (int idx = tid; idx < 4096; idx += 256) {
        int c = idx >> 6, j = idx & 63;
        xs[c][j] = ftr[((size_t)(b * CC + c)) * PP + p0 + j];
    }
    for (int idx = tid; idx < 1024; idx += 256) {
        wqs[idx >> 6][idx & 63] = wq[idx];
        wks[idx >> 6][idx & 63] = wk[idx];
    }
    for (int idx = tid; idx < 4096; idx += 256) {
        wvs[idx >> 6][idx & 63] = wv[idx];
    }
    __syncthreads();

    int j = tid & 63;
    int g = tid >> 6;   // 0..3

    // q, k: each thread does 4 of the 16 output channels for its column j
    #pragma unroll
    for (int oo = 0; oo < 4; ++oo) {
        int o = g * 4 + oo;
        float sq = bq[o], sk = bk[o];
        #pragma unroll 8
        for (int c = 0; c < 64; ++c) {
            float xv = xs[c][j];
            sq += wqs[o][c] * xv;
            sk += wks[o][c] * xv;
        }
        q_out[(((size_t)b * PP) + p0 + j) * CI + o] = sq;
        k_out[((size_t)(b * CI + o)) * PP + p0 + j] = sk;
    }
    // v: each thread does 16 of the 64 output channels
    #pragma unroll
    for (int ccx = 0; ccx < 16; ++ccx) {
        int c = g * 16 + ccx;
        float sv = bv[c];
        #pragma unroll 8
        for (int c2 = 0; c2 < 64; ++c2) {
            sv += wvs[c][c2] * xs[c2][j];
        }
        v_out[((size_t)(b * CC + c)) * PP + p0 + j] = sv;
    }
}

// ---------------------------------------------------------------------------
// Kernel 2: flash-style attention with softmax over p (columns of S).
// Block handles (b, 32 output columns). Online softmax over p-tiles of 64.
// Fuses out = delta * G + ftr  -> d_out.
// grid = B * (P/32) = 512 blocks, 256 threads.
// Thread t owns column j = t&31 and 8 channels cbase = (t>>5)*8.
// ---------------------------------------------------------------------------
__global__ __launch_bounds__(256) void attn_kernel(
    const float* __restrict__ q, const float* __restrict__ k, const float* __restrict__ v,
    const float* __restrict__ ftr, const float* __restrict__ delta,
    float* __restrict__ out)
{
    __shared__ float Ks[CI][32];    // k[b, o, j0+j]
    __shared__ float Qs[64][CI];    // q[b, pt+p, o]
    __shared__ float Vs[64][65];    // v[b, c, pt+pp], padded
    __shared__ float st[64][33];    // scores then exp-weights, padded
    __shared__ float pmax[8][32];
    __shared__ float psum[8][32];
    __shared__ float mcol[32], lcol[32], sccol[32];

    int b  = blockIdx.x >> 7;
    int j0 = (blockIdx.x & 127) << 5;
    int tid = threadIdx.x;
    int j = tid & 31;
    int g = tid >> 5;       // 0..7
    int cbase = g * 8;

    for (int idx = tid; idx < CI * 32; idx += 256) {
        int o = idx >> 5, jj = idx & 31;
        Ks[o][jj] = k[((size_t)(b * CI + o)) * PP + j0 + jj];
    }
    if (tid < 32) { mcol[tid] = -__builtin_huge_valf(); lcol[tid] = 0.f; }

    float acc[8];
    #pragma unroll
    for (int i = 0; i < 8; ++i) acc[i] = 0.f;

    for (int pt = 0; pt < PP; pt += 64) {
        // stage Q tile [64][16] and V tile [64][64]
        for (int idx = tid; idx < 64 * CI; idx += 256) {
            int p = idx >> 4, o = idx & 15;
            Qs[p][o] = q[(((size_t)b * PP) + pt + p) * CI + o];
        }
        for (int idx = tid; idx < 64 * 64; idx += 256) {
            int c = idx >> 6, pp = idx & 63;
            Vs[c][pp] = v[((size_t)(b * CC + c)) * PP + pt + pp];
        }
        __syncthreads();

        // scores: thread computes s[p][j] for 8 rows p = g*8 + i
        float lmax = -__builtin_huge_valf();
        #pragma unroll
        for (int i = 0; i < 8; ++i) {
            int p = g * 8 + i;
            float s = 0.f;
            #pragma unroll
            for (int o = 0; o < CI; ++o) s += Qs[p][o] * Ks[o][j];
            st[p][j] = s;
            lmax = fmaxf(lmax, s);
        }
        pmax[g][j] = lmax;
        __syncthreads();

        // per-column running max + rescale factor
        if (tid < 32) {
            float tm = pmax[0][tid];
            #pragma unroll
            for (int i = 1; i < 8; ++i) tm = fmaxf(tm, pmax[i][tid]);
            float m_old = mcol[tid];
            float m_new = fmaxf(m_old, tm);
            mcol[tid] = m_new;
            sccol[tid] = expf(m_old - m_new);   // 0 on first tile (exp(-inf))
        }
        __syncthreads();

        // exponentiate in place + partial sums
        float mj = mcol[j];
        float lsum = 0.f;
        #pragma unroll
        for (int i = 0; i < 8; ++i) {
            int p = g * 8 + i;
            float w = expf(st[p][j] - mj);
            st[p][j] = w;
            lsum += w;
        }
        psum[g][j] = lsum;
        __syncthreads();

        if (tid < 32) {
            float ts = 0.f;
            #pragma unroll
            for (int i = 0; i < 8; ++i) ts += psum[i][tid];
            lcol[tid] = lcol[tid] * sccol[tid] + ts;
        }

        // accumulate G: acc[c][j] = acc*scale + V[c, pt:pt+64] . w[:, j]
        float sc = sccol[j];
        #pragma unroll
        for (int i = 0; i < 8; ++i) acc[i] *= sc;
        for (int pp = 0; pp < 64; ++pp) {
            float w = st[pp][j];
            #pragma unroll
            for (int i = 0; i < 8; ++i) acc[i] += Vs[cbase + i][pp] * w;
        }
        __syncthreads();
    }

    float dlt = delta[0];
    float linv = 1.f / lcol[j];
    #pragma unroll
    for (int i = 0; i < 8; ++i) {
        size_t oidx = ((size_t)(b * CC + cbase + i)) * PP + j0 + j;
        out[oidx] = dlt * acc[i] * linv + ftr[oidx];
    }
}

// ---------------------------------------------------------------------------
// Kernel 3: per (b,c) avg + max over P. grid = B*C = 256 blocks, 256 threads.
// ---------------------------------------------------------------------------
__global__ __launch_bounds__(256) void stats_kernel(
    const float* __restrict__ out, float* __restrict__ f_avg, float* __restrict__ f_max)
{
    int bc = blockIdx.x;
    const float* base = out + (size_t)bc * PP;
    int tid = threadIdx.x;
    float s = 0.f, m = -__builtin_huge_valf();
    for (int i = tid; i < PP; i += 256) {
        float v = base[i];
        s += v;
        m = fmaxf(m, v);
    }
    __shared__ float rs[256], rm[256];
    rs[tid] = s; rm[tid] = m;
    __syncthreads();
    for (int off = 128; off > 0; off >>= 1) {
        if (tid < off) {
            rs[tid] += rs[tid + off];
            rm[tid] = fmaxf(rm[tid], rm[tid + off]);
        }
        __syncthreads();
    }
    if (tid == 0) {
        f_avg[bc] = rs[0] * (1.f / PP);
        f_max[bc] = rm[0];
    }
}

// ---------------------------------------------------------------------------
// Kernel 4: SE MLP gate. grid = B blocks, 64 threads.
// ---------------------------------------------------------------------------
__global__ __launch_bounds__(64) void gate_kernel(
    const float* __restrict__ f_avg, const float* __restrict__ f_max,
    const float* __restrict__ w_avg1, const float* __restrict__ w_avg2,
    const float* __restrict__ w_max1, const float* __restrict__ w_max2,
    float* __restrict__ gate)
{
    int b = blockIdx.x;
    int t = threadIdx.x;
    __shared__ float fa[64], fm[64], ha[16], hm[16];
    fa[t] = f_avg[b * 64 + t];
    fm[t] = f_max[b * 64 + t];
    __syncthreads();
    if (t < 16) {
        float s = 0.f;
        for (int c = 0; c < 64; ++c) s += fa[c] * w_avg1[t * 64 + c];
        ha[t] = fmaxf(s, 0.f);
    } else if (t < 32) {
        int i = t - 16;
        float s = 0.f;
        for (int c = 0; c < 64; ++c) s += fm[c] * w_max1[i * 64 + c];
        hm[i] = fmaxf(s, 0.f);
    }
    __syncthreads();
    float a = 0.f, mm = 0.f;
    #pragma unroll
    for (int i = 0; i < 16; ++i) {
        a  += ha[i] * w_avg2[t * 16 + i];
        mm += hm[i] * w_max2[t * 16 + i];
    }
    gate[b * 64 + t] = 1.f / (1.f + expf(-(a + mm)));
}

// ---------------------------------------------------------------------------
// Kernel 5: in-place gate multiply. 1048576 elements.
// ---------------------------------------------------------------------------
__global__ __launch_bounds__(256) void mul_kernel(
    float* __restrict__ out, const float* __restrict__ gate)
{
    int idx = blockIdx.x * 256 + threadIdx.x;
    out[idx] *= gate[idx >> 12];
}

// ---------------------------------------------------------------------------
extern "C" void kernel_launch(void* const* d_in, const int* in_sizes, int n_in,
                              void* d_out, int out_size, void* d_ws, size_t ws_size,
                              hipStream_t stream)
{
    const float* ftr    = (const float*)d_in[0];
    const float* wq     = (const float*)d_in[1];
    const float* bq     = (const float*)d_in[2];
    const float* wk     = (const float*)d_in[3];
    const float* bk     = (const float*)d_in[4];
    const float* wv     = (const float*)d_in[5];
    const float* bv     = (const float*)d_in[6];
    const float* delta  = (const float*)d_in[7];
    const float* w_avg1 = (const float*)d_in[8];
    const float* w_avg2 = (const float*)d_in[9];
    const float* w_max1 = (const float*)d_in[10];
    const float* w_max2 = (const float*)d_in[11];
    float* out = (float*)d_out;

    float* ws = (float*)d_ws;
    float* q_ws  = ws;                 // B*P*CI  = 262144
    float* k_ws  = ws + 262144;        // B*CI*P  = 262144
    float* v_ws  = ws + 524288;        // B*C*P   = 1048576
    float* f_avg = ws + 1572864;       // B*C = 256
    float* f_max = ws + 1573120;       // 256
    float* gate  = ws + 1573376;       // 256
    // total: 1573632 floats = 6.29 MB of workspace

    qkv_kernel<<<256, 256, 0, stream>>>(ftr, wq, bq, wk, bk, wv, bv, q_ws, k_ws, v_ws);
    attn_kernel<<<512, 256, 0, stream>>>(q_ws, k_ws, v_ws, ftr, delta, out);
    stats_kernel<<<256, 256, 0, stream>>>(out, f_avg, f_max);
    gate_kernel<<<4, 64, 0, stream>>>(f_avg, f_max, w_avg1, w_avg2, w_max1, w_max2, gate);
    mul_kernel<<<4096, 256, 0, stream>>>(out, gate);
}

// Round 2
// 162.451 us; speedup vs baseline: 4.5217x; 4.5217x over previous
//
#include <hip/hip_runtime.h>
#include <math.h>

#define BB 4
#define CC 64
#define PP 4096
#define CI 16

typedef __attribute__((ext_vector_type(8))) short short8;
typedef __attribute__((ext_vector_type(4))) short short4v;
typedef __attribute__((ext_vector_type(4))) float float4v;

__device__ __forceinline__ short f2bf(float f) {
    union { float f; unsigned u; } v; v.f = f;
    unsigned r = v.u + 0x7FFFu + ((v.u >> 16) & 1u);
    return (short)(r >> 16);
}

// ---------------------------------------------------------------------------
// Kernel 1: q/k/v projections -> bf16 in MFMA-friendly layouts.
//   q_pad, k_pad: [B, P, 32] bf16, channels 0..15 real, 16..31 zero.
//   v_sw: B-fragment-swizzled: [b][p/32][c/16][lane(=c%16 + 16*((p>>3)&3))][p&7]
// grid = B * (P/64) = 256 blocks, 256 threads.
// ---------------------------------------------------------------------------
__global__ __launch_bounds__(256) void qkv_kernel(
    const float* __restrict__ ftr, const float* __restrict__ wq, const float* __restrict__ bq,
    const float* __restrict__ wk, const float* __restrict__ bk,
    const float* __restrict__ wv, const float* __restrict__ bv,
    short* __restrict__ q_pad, short* __restrict__ k_pad, short* __restrict__ v_sw)
{
    __shared__ float xs[64][65];
    __shared__ float wqs[16][64];
    __shared__ float wks[16][64];
    __shared__ float wvs[64][64];

    int b  = blockIdx.x >> 6;
    int p0 = (blockIdx.x & 63) << 6;
    int tid = threadIdx.x;

    for (int idx = tid; idx < 4096; idx += 256) {
        int c = idx >> 6, j = idx & 63;
        xs[c][j] = ftr[((size_t)(b * CC + c)) * PP + p0 + j];
    }
    for (int idx = tid; idx < 1024; idx += 256) {
        wqs[idx >> 6][idx & 63] = wq[idx];
        wks[idx >> 6][idx & 63] = wk[idx];
    }
    for (int idx = tid; idx < 4096; idx += 256) {
        wvs[idx >> 6][idx & 63] = wv[idx];
    }
    __syncthreads();

    int j = tid & 63;
    int g = tid >> 6;        // 0..3
    int p = p0 + j;
    size_t row = ((size_t)(b * PP + p)) * 32;

    #pragma unroll
    for (int oo = 0; oo < 4; ++oo) {
        int o = g * 4 + oo;
        float sq = bq[o], sk = bk[o];
        #pragma unroll 8
        for (int c = 0; c < 64; ++c) {
            float xv = xs[c][j];
            sq += wqs[o][c] * xv;
            sk += wks[o][c] * xv;
        }
        q_pad[row + o] = f2bf(sq);  q_pad[row + o + 16] = 0;
        k_pad[row + o] = f2bf(sk);  k_pad[row + o + 16] = 0;
    }
    // v -> swizzled B-fragment order
    int ktg  = p >> 5;
    int quad = (p >> 3) & 3;
    int jj   = p & 7;
    #pragma unroll
    for (int cc = 0; cc < 16; ++cc) {
        int c = g * 16 + cc;
        float sv = bv[c];
        #pragma unroll 8
        for (int c2 = 0; c2 < 64; ++c2) sv += wvs[c][c2] * xs[c2][j];
        size_t addr = ((((size_t)(b * 128 + ktg)) * 4 + g) * 64 + (cc + (quad << 4))) * 8 + jj;
        v_sw[addr] = f2bf(sv);
    }
}

// ---------------------------------------------------------------------------
// Kernel 2: MFMA flash attention, softmax over p (axis=1).
// Block: 256 thr = 4 waves. wave wid: rt = wid&1 (q' rows rt*16..+15 of the
// block's 32), ph = wid>>1 (p half: ph*2048..+2047). Epilogue merges halves
// in LDS, normalizes, adds delta*G + ftr, coalesced store.
// grid = B * (P/32) = 512 blocks.
// ---------------------------------------------------------------------------
__global__ __launch_bounds__(256, 2) void attn_kernel(
    const short* __restrict__ q_pad, const short* __restrict__ k_pad,
    const short* __restrict__ v_sw,
    const float* __restrict__ ftr, const float* __restrict__ delta,
    float* __restrict__ out)
{
    __shared__ char smem[20480] __attribute__((aligned(16)));
    short* Wt   = (short*)smem;                 // [4 waves][16 rows][72] bf16 = 9216 B (main loop)
    float* mlb  = (float*)smem;                 // [2 rt][2 ph][16 n][2]  (epilogue)
    float* Obuf = (float*)(smem + 512);         // [2 rt][16][66] fp32
    float* Oe   = (float*)(smem + 512 + 8448);  // [64 c][40] fp32

    int b   = blockIdx.x >> 7;
    int q0  = (blockIdx.x & 127) << 5;
    int tid = threadIdx.x;
    int lane = tid & 63;
    int n    = lane & 15;
    int quad = lane >> 4;
    int wid  = tid >> 6;
    int rt   = wid & 1;
    int ph   = wid >> 1;

    float delta0 = delta[0];

    // K (B-operand for scores) — wave-constant
    const short8 bk = *(const short8*)(k_pad + ((size_t)(b * PP + q0 + rt * 16 + n)) * 32 + quad * 8);

    const short* qbase = q_pad + ((size_t)(b * PP + n)) * 32 + quad * 8;
    const short* vbase = v_sw + (size_t)b * 262144 + lane * 8;
    short* wrow = Wt + (wid * 16 + n) * 72;
    short* wrd  = Wt + (wid * 16 + n) * 72;   // A-frag read row (m = lane&15 = n)

    float4v acc[4];
    #pragma unroll
    for (int nt = 0; nt < 4; ++nt) acc[nt] = (float4v){0.f, 0.f, 0.f, 0.f};
    float m_run = -__builtin_huge_valf();
    float l_run = 0.f;

    int srcbase = quad * 20;   // quad*16 + quad*4 : lane holding column n == quad*4+r

    short8 aqb[2][4];
    {
        const short* qb = qbase + (size_t)(ph * 2048) * 32;
        #pragma unroll
        for (int f = 0; f < 4; ++f) aqb[0][f] = *(const short8*)(qb + (size_t)f * 16 * 32);
    }

    #pragma unroll 2
    for (int it = 0; it < 32; ++it) {
        const int cb = it & 1;

        // V B-fragments for this iter (coalesced 1KB loads; consumed after softmax)
        short8 vf[8];
        int ktg0 = ph * 64 + it * 2;
        #pragma unroll
        for (int kt = 0; kt < 2; ++kt)
            #pragma unroll
            for (int nt = 0; nt < 4; ++nt)
                vf[kt * 4 + nt] = *(const short8*)(vbase + (size_t)((ktg0 + kt) * 4 + nt) * 512);

        // prefetch next iter's A fragments
        if (it < 31) {
            const short* qb = qbase + (size_t)(ph * 2048 + (it + 1) * 64) * 32;
            #pragma unroll
            for (int f = 0; f < 4; ++f) aqb[cb ^ 1][f] = *(const short8*)(qb + (size_t)f * 16 * 32);
        }

        // scores: S[p][q'], M=p (rows quad*4+reg per 16-tile f), N=q' (col n)
        float4v sf[4];
        #pragma unroll
        for (int f = 0; f < 4; ++f)
            sf[f] = __builtin_amdgcn_mfma_f32_16x16x32_bf16(aqb[cb][f], bk,
                        (float4v){0.f, 0.f, 0.f, 0.f}, 0, 0, 0);

        // online softmax over p: in-lane max of 16, then 2 cross-quad shuffles
        float tm = sf[0][0];
        #pragma unroll
        for (int f = 0; f < 4; ++f)
            #pragma unroll
            for (int r = 0; r < 4; ++r) tm = fmaxf(tm, sf[f][r]);
        tm = fmaxf(tm, __shfl_xor(tm, 16));
        tm = fmaxf(tm, __shfl_xor(tm, 32));
        float mn = fmaxf(m_run, tm);
        float e  = __expf(m_run - mn);    // first iter: exp(-inf)=0
        m_run = mn;

        float w[4][4];
        float ls = 0.f;
        #pragma unroll
        for (int f = 0; f < 4; ++f)
            #pragma unroll
            for (int r = 0; r < 4; ++r) {
                float ww = __expf(sf[f][r] - mn);
                w[f][r] = ww;
                ls += ww;
            }
        l_run = l_run * e + ls;

        // row-keyed alpha for accumulator rescale
        float ar[4];
        #pragma unroll
        for (int r = 0; r < 4; ++r) ar[r] = __shfl(e, srcbase + r);
        #pragma unroll
        for (int nt = 0; nt < 4; ++nt)
            #pragma unroll
            for (int r = 0; r < 4; ++r) acc[nt][r] *= ar[r];

        // transpose weights (C-layout -> A-layout) through per-wave LDS tile
        #pragma unroll
        for (int f = 0; f < 4; ++f) {
            short4v pk;
            #pragma unroll
            for (int r = 0; r < 4; ++r) pk[r] = f2bf(w[f][r]);
            *(short4v*)(wrow + f * 16 + quad * 4) = pk;
        }
        short8 wa[2];
        #pragma unroll
        for (int kt = 0; kt < 2; ++kt)
            wa[kt] = *(const short8*)(wrd + kt * 32 + quad * 8);

        // PV: O[q'][c] += W~[q'][p] V[p][c]
        #pragma unroll
        for (int kt = 0; kt < 2; ++kt)
            #pragma unroll
            for (int nt = 0; nt < 4; ++nt)
                acc[nt] = __builtin_amdgcn_mfma_f32_16x16x32_bf16(wa[kt], vf[kt * 4 + nt], acc[nt], 0, 0, 0);
    }

    // ---- epilogue: merge quads' l, merge p-halves, normalize, store ----
    l_run += __shfl_xor(l_run, 16);
    l_run += __shfl_xor(l_run, 32);

    __syncthreads();   // done with Wt; smem reused
    if (quad == 0) {
        mlb[((rt * 2 + ph) * 16 + n) * 2 + 0] = m_run;
        mlb[((rt * 2 + ph) * 16 + n) * 2 + 1] = l_run;
    }
    __syncthreads();
    float m0 = mlb[((rt * 2 + 0) * 16 + n) * 2 + 0];
    float l0 = mlb[((rt * 2 + 0) * 16 + n) * 2 + 1];
    float m1 = mlb[((rt * 2 + 1) * 16 + n) * 2 + 0];
    float l1 = mlb[((rt * 2 + 1) * 16 + n) * 2 + 1];
    float M  = fmaxf(m0, m1);
    float a0 = __expf(m0 - M), a1 = __expf(m1 - M);
    float lf = a0 * l0 + a1 * l1;
    float aph = ph ? a1 : a0;             // column-keyed
    float dln = delta0 / lf;              // column-keyed

    float ar[4], lr[4];
    #pragma unroll
    for (int r = 0; r < 4; ++r) {
        ar[r] = __shfl(aph, srcbase + r);
        lr[r] = __shfl(dln, srcbase + r);
    }

    if (ph == 1) {
        #pragma unroll
        for (int nt = 0; nt < 4; ++nt)
            #pragma unroll
            for (int r = 0; r < 4; ++r)
                Obuf[(rt * 16 + quad * 4 + r) * 66 + nt * 16 + n] = acc[nt][r] * ar[r];
    }
    __syncthreads();
    if (ph == 0) {
        #pragma unroll
        for (int nt = 0; nt < 4; ++nt)
            #pragma unroll
            for (int r = 0; r < 4; ++r) {
                float o = acc[nt][r] * ar[r] + Obuf[(rt * 16 + quad * 4 + r) * 66 + nt * 16 + n];
                Oe[(nt * 16 + n) * 40 + rt * 16 + quad * 4 + r] = o * lr[r];
            }
    }
    __syncthreads();

    // coalesced store: out = Oe + ftr
    int c  = tid >> 2;
    int qp = tid & 3;
    size_t gaddr = ((size_t)(b * CC + c)) * PP + q0 + qp * 8;
    float4 x0 = *(const float4*)(Oe + c * 40 + qp * 8);
    float4 x1 = *(const float4*)(Oe + c * 40 + qp * 8 + 4);
    float4 f0 = *(const float4*)(ftr + gaddr);
    float4 f1 = *(const float4*)(ftr + gaddr + 4);
    x0.x += f0.x; x0.y += f0.y; x0.z += f0.z; x0.w += f0.w;
    x1.x += f1.x; x1.y += f1.y; x1.z += f1.z; x1.w += f1.w;
    *(float4*)(out + gaddr)     = x0;
    *(float4*)(out + gaddr + 4) = x1;
}

// ---------------------------------------------------------------------------
// Kernel 3: per (b,c) avg + max over P.
// ---------------------------------------------------------------------------
__global__ __launch_bounds__(256) void stats_kernel(
    const float* __restrict__ out, float* __restrict__ f_avg, float* __restrict__ f_max)
{
    int bc = blockIdx.x;
    const float* base = out + (size_t)bc * PP;
    int tid = threadIdx.x;
    float s = 0.f, m = -__builtin_huge_valf();
    for (int i = tid; i < PP; i += 256) {
        float v = base[i];
        s += v;
        m = fmaxf(m, v);
    }
    __shared__ float rs[256], rm[256];
    rs[tid] = s; rm[tid] = m;
    __syncthreads();
    for (int off = 128; off > 0; off >>= 1) {
        if (tid < off) {
            rs[tid] += rs[tid + off];
            rm[tid] = fmaxf(rm[tid], rm[tid + off]);
        }
        __syncthreads();
    }
    if (tid == 0) {
        f_avg[bc] = rs[0] * (1.f / PP);
        f_max[bc] = rm[0];
    }
}

// ---------------------------------------------------------------------------
// Kernel 4: SE MLP gate.
// ---------------------------------------------------------------------------
__global__ __launch_bounds__(64) void gate_kernel(
    const float* __restrict__ f_avg, const float* __restrict__ f_max,
    const float* __restrict__ w_avg1, const float* __restrict__ w_avg2,
    const float* __restrict__ w_max1, const float* __restrict__ w_max2,
    float* __restrict__ gate)
{
    int b = blockIdx.x;
    int t = threadIdx.x;
    __shared__ float fa[64], fm[64], ha[16], hm[16];
    fa[t] = f_avg[b * 64 + t];
    fm[t] = f_max[b * 64 + t];
    __syncthreads();
    if (t < 16) {
        float s = 0.f;
        for (int c = 0; c < 64; ++c) s += fa[c] * w_avg1[t * 64 + c];
        ha[t] = fmaxf(s, 0.f);
    } else if (t < 32) {
        int i = t - 16;
        float s = 0.f;
        for (int c = 0; c < 64; ++c) s += fm[c] * w_max1[i * 64 + c];
        hm[i] = fmaxf(s, 0.f);
    }
    __syncthreads();
    float a = 0.f, mm = 0.f;
    #pragma unroll
    for (int i = 0; i < 16; ++i) {
        a  += ha[i] * w_avg2[t * 16 + i];
        mm += hm[i] * w_max2[t * 16 + i];
    }
    gate[b * 64 + t] = 1.f / (1.f + expf(-(a + mm)));
}

// ---------------------------------------------------------------------------
// Kernel 5: in-place gate multiply.
// ---------------------------------------------------------------------------
__global__ __launch_bounds__(256) void mul_kernel(
    float* __restrict__ out, const float* __restrict__ gate)
{
    int idx = blockIdx.x * 256 + threadIdx.x;
    out[idx] *= gate[idx >> 12];
}

// ---------------------------------------------------------------------------
extern "C" void kernel_launch(void* const* d_in, const int* in_sizes, int n_in,
                              void* d_out, int out_size, void* d_ws, size_t ws_size,
                              hipStream_t stream)
{
    const float* ftr    = (const float*)d_in[0];
    const float* wq     = (const float*)d_in[1];
    const float* bq     = (const float*)d_in[2];
    const float* wk     = (const float*)d_in[3];
    const float* bk     = (const float*)d_in[4];
    const float* wv     = (const float*)d_in[5];
    const float* bv     = (const float*)d_in[6];
    const float* delta  = (const float*)d_in[7];
    const float* w_avg1 = (const float*)d_in[8];
    const float* w_avg2 = (const float*)d_in[9];
    const float* w_max1 = (const float*)d_in[10];
    const float* w_max2 = (const float*)d_in[11];
    float* out = (float*)d_out;

    short* q_pad = (short*)d_ws;               // [4][4096][32] bf16 = 1 MB
    short* k_pad = q_pad + 524288;             // 1 MB
    short* v_sw  = k_pad + 524288;             // 2 MB
    float* f_avg = (float*)(v_sw + 1048576);
    float* f_max = f_avg + 256;
    float* gate  = f_max + 256;

    qkv_kernel<<<256, 256, 0, stream>>>(ftr, wq, bq, wk, bk, wv, bv, q_pad, k_pad, v_sw);
    attn_kernel<<<512, 256, 0, stream>>>(q_pad, k_pad, v_sw, ftr, delta, out);
    stats_kernel<<<256, 256, 0, stream>>>(out, f_avg, f_max);
    gate_kernel<<<4, 64, 0, stream>>>(f_avg, f_max, w_avg1, w_avg2, w_max1, w_max2, gate);
    mul_kernel<<<4096, 256, 0, stream>>>(out, gate);
}

// Round 3
// 125.049 us; speedup vs baseline: 5.8741x; 1.2991x over previous
//
#include <hip/hip_runtime.h>
#include <math.h>

#define PP 4096

typedef __attribute__((ext_vector_type(8))) short short8;
typedef __attribute__((ext_vector_type(4))) float float4v;

__device__ __forceinline__ short f2bf(float f) {
    union { float f; unsigned u; } v; v.f = f;
    unsigned r = v.u + 0x7FFFu + ((v.u >> 16) & 1u);
    return (short)(r >> 16);
}

// ---------------------------------------------------------------------------
// Kernel 1: q/k/v projections -> bf16.
//   q16, k16: [B, P, 16] bf16 (16 channels, no padding; q pre-scaled by log2e)
//   v_sw: B-fragment-swizzled: [b][p/32][c/16][(p>>3)&3][c%16][p&7]
// grid = B * (P/64) = 256 blocks, 256 threads. All stores are 16B coalesced.
// ---------------------------------------------------------------------------
__global__ __launch_bounds__(256) void qkv_kernel(
    const float* __restrict__ ftr, const float* __restrict__ wq, const float* __restrict__ bq,
    const float* __restrict__ wk, const float* __restrict__ bk,
    const float* __restrict__ wv, const float* __restrict__ bv,
    short* __restrict__ q16, short* __restrict__ k16, short* __restrict__ v_sw)
{
    __shared__ float xs[64][68] __attribute__((aligned(16)));    // x[c][p-local]
    __shared__ float wvs[64][68] __attribute__((aligned(16)));   // wv[c][c2]
    __shared__ float wq_t[64][20] __attribute__((aligned(16)));  // wq^T[c2][o]
    __shared__ float wk_t[64][20] __attribute__((aligned(16)));  // wk^T[c2][o]

    const int b  = blockIdx.x >> 6;
    const int p0 = (blockIdx.x & 63) << 6;
    const int tid = threadIdx.x;

    for (int idx = tid; idx < 1024; idx += 256) {   // ftr tile, float4
        int c = idx >> 4, j4 = (idx & 15) << 2;
        *(float4*)&xs[c][j4] = *(const float4*)(ftr + ((size_t)(b * 64 + c)) * PP + p0 + j4);
    }
    for (int idx = tid; idx < 1024; idx += 256) {   // wv, float4
        int r = idx >> 4, j4 = (idx & 15) << 2;
        *(float4*)&wvs[r][j4] = *(const float4*)(wv + r * 64 + j4);
    }
    for (int idx = tid; idx < 1024; idx += 256) {   // wq/wk transposed
        int o = idx >> 6, c2 = idx & 63;
        wq_t[c2][o] = wq[idx];
        wk_t[c2][o] = wk[idx];
    }
    __syncthreads();

    // ---- v: thread (wg=c-group, qd=p-octet-in-32, cc) -> 8 p's of one c ----
    {
        const int wg = tid >> 6, qd = (tid >> 4) & 3, cc = tid & 15;
        const int c = wg * 16 + cc;
        const int ktg0 = p0 >> 5;
        const float bvc = bv[c];
        #pragma unroll
        for (int kt = 0; kt < 2; ++kt) {
            const int col = kt * 32 + qd * 8;
            float a[8] = {0.f,0.f,0.f,0.f,0.f,0.f,0.f,0.f};
            #pragma unroll 8
            for (int c2 = 0; c2 < 64; ++c2) {
                float w = wvs[c][c2];
                float4 xa = *(const float4*)&xs[c2][col];
                float4 xb = *(const float4*)&xs[c2][col + 4];
                a[0] += w * xa.x; a[1] += w * xa.y; a[2] += w * xa.z; a[3] += w * xa.w;
                a[4] += w * xb.x; a[5] += w * xb.y; a[6] += w * xb.z; a[7] += w * xb.w;
            }
            short8 pv;
            #pragma unroll
            for (int jj = 0; jj < 8; ++jj) pv[jj] = f2bf(a[jj] + bvc);
            *(short8*)(v_sw + ((size_t)(b * 128 + ktg0 + kt)) * 2048 + tid * 8) = pv;
        }
    }

    // ---- q/k: thread (p_l, sel) -> 8 channels of one p for q or k ----
    {
        const int p_l = tid >> 2, sel = tid & 3;
        const int half = sel & 1, arr = sel >> 1;
        const float* Wtr = arr ? &wk_t[0][0] : &wq_t[0][0];
        float a[8] = {0.f,0.f,0.f,0.f,0.f,0.f,0.f,0.f};
        #pragma unroll 8
        for (int c2 = 0; c2 < 64; ++c2) {
            float x = xs[c2][p_l];
            float4 wA = *(const float4*)(Wtr + c2 * 20 + half * 8);
            float4 wB = *(const float4*)(Wtr + c2 * 20 + half * 8 + 4);
            a[0] += wA.x * x; a[1] += wA.y * x; a[2] += wA.z * x; a[3] += wA.w * x;
            a[4] += wB.x * x; a[5] += wB.y * x; a[6] += wB.z * x; a[7] += wB.w * x;
        }
        const float* bias = arr ? bk : bq;
        const float scl = arr ? 1.0f : 1.4426950408889634f;   // log2(e) folded into q
        short8 pq;
        #pragma unroll
        for (int oo = 0; oo < 8; ++oo)
            pq[oo] = f2bf((a[oo] + bias[half * 8 + oo]) * scl);
        short* dst = (arr ? k16 : q16) + (((size_t)(b * PP + p0 + p_l)) << 4) + half * 8;
        *(short8*)dst = pq;
    }
}

// ---------------------------------------------------------------------------
// Kernel 2: MFMA flash attention, softmax over p (axis=1), no running max
// (scores bounded, exp2 can't overflow fp32). Block = 32 q' columns; 4 waves,
// wave ph owns p-quarter. No barriers in the main loop. Epilogue merges the 4
// partials, normalizes, adds delta*G + ftr, emits per-block stats partials.
// grid = B * 128 = 512 blocks, 256 threads.
// ---------------------------------------------------------------------------
__global__ __launch_bounds__(256, 2) void attn_kernel(
    const short* __restrict__ q16, const short* __restrict__ k16,
    const short* __restrict__ v_sw,
    const float* __restrict__ ftr, const float* __restrict__ delta,
    float* __restrict__ out, float* __restrict__ psum, float* __restrict__ pmax)
{
    __shared__ char smem[34304] __attribute__((aligned(16)));
    short* Wt   = (short*)smem;                  // main loop: [4 waves][32 rows][64] bf16 (16 KB)
    float* Obuf = (float*)smem;                  // epilogue: [4 ph][32 q][66 c] fp32 (33792 B)
    float* lb   = (float*)(smem + 33792);        // [4 ph][32 q] (512 B, disjoint from Wt/Obuf)

    const int b    = blockIdx.x >> 7;
    const int qblk = blockIdx.x & 127;
    const int q0   = qblk << 5;
    const int tid  = threadIdx.x;
    const int lane = tid & 63;
    const int n    = lane & 15;
    const int quad = lane >> 4;
    const int ph   = tid >> 6;

    const short8 z8 = {0,0,0,0,0,0,0,0};
    const float4v zf4 = {0.f,0.f,0.f,0.f};

    // K B-fragments (wave-constant): B[k=quad*8+j][q'=n]; k>=16 is zero.
    short8 bkf[2];
    #pragma unroll
    for (int mt = 0; mt < 2; ++mt) {
        bkf[mt] = z8;
        if (quad < 2)
            bkf[mt] = *(const short8*)(k16 + ((size_t)(b * PP + q0 + mt * 16 + n) << 4) + quad * 8);
    }

    const short* vbase = v_sw + (size_t)b * 262144 + lane * 8;
    const short* qbase = q16 + ((size_t)(b * PP + n) << 4) + (quad & 1) * 8;
    short* wbase = Wt + ph * 2048;   // per-wave region: 32 rows x 128B, XOR-swizzled

    float4v acc[2][4];
    #pragma unroll
    for (int mt = 0; mt < 2; ++mt)
        #pragma unroll
        for (int nt = 0; nt < 4; ++nt) acc[mt][nt] = zf4;
    float lsum[2] = {0.f, 0.f};

    const int pt0 = ph * 1024;
    short8 aq[2][4];
    #pragma unroll
    for (int f = 0; f < 4; ++f) { aq[0][f] = z8; aq[1][f] = z8; }
    if (quad < 2) {
        #pragma unroll
        for (int f = 0; f < 4; ++f)
            aq[0][f] = *(const short8*)(qbase + (size_t)(pt0 + f * 16) * 16);
    }

    #pragma unroll 2
    for (int it = 0; it < 16; ++it) {
        const int cb = it & 1;
        const int pt = pt0 + it * 64;
        const int ktg0 = pt >> 5;

        // V B-frags for this iter (coalesced 1KB wave loads from L2)
        short8 vf[2][4];
        #pragma unroll
        for (int kt = 0; kt < 2; ++kt)
            #pragma unroll
            for (int nt = 0; nt < 4; ++nt)
                vf[kt][nt] = *(const short8*)(vbase + (size_t)((ktg0 + kt) * 4 + nt) * 512);

        // prefetch next iter's Q A-frags
        if (it < 15 && quad < 2) {
            const short* qb = qbase + (size_t)(pt + 64) * 16;
            #pragma unroll
            for (int f = 0; f < 4; ++f)
                aq[cb ^ 1][f] = *(const short8*)(qb + f * 256);
        }

        // scores: S[p][q'] ; M=p (4 tiles of 16), N=q' (2 tiles of 16)
        float4v sf[4][2];
        #pragma unroll
        for (int f = 0; f < 4; ++f)
            #pragma unroll
            for (int mt = 0; mt < 2; ++mt)
                sf[f][mt] = __builtin_amdgcn_mfma_f32_16x16x32_bf16(aq[cb][f], bkf[mt], zf4, 0, 0, 0);

        // exp2 (log2e pre-folded), accumulate l, pack bf16, swizzled LDS write
        #pragma unroll
        for (int mt = 0; mt < 2; ++mt) {
            short* wrow = wbase + (mt * 16 + n) * 64;
            #pragma unroll
            for (int f = 0; f < 4; ++f) {
                float w0 = __builtin_amdgcn_exp2f(sf[f][mt][0]);
                float w1 = __builtin_amdgcn_exp2f(sf[f][mt][1]);
                float w2 = __builtin_amdgcn_exp2f(sf[f][mt][2]);
                float w3 = __builtin_amdgcn_exp2f(sf[f][mt][3]);
                lsum[mt] += (w0 + w1) + (w2 + w3);
                uint2 pk;
                pk.x = __builtin_amdgcn_perm(__float_as_uint(w1), __float_as_uint(w0), 0x07060302u);
                pk.y = __builtin_amdgcn_perm(__float_as_uint(w3), __float_as_uint(w2), 0x07060302u);
                const int g = (f * 4 + quad) ^ ((n & 7) << 1);   // 8B-granule XOR swizzle
                *(uint2*)(wrow + g * 4) = pk;
            }
        }

        // read W~ A-frags (b128, swizzle-matched), then PV MFMAs
        short8 wa[2][2];
        #pragma unroll
        for (int mt = 0; mt < 2; ++mt) {
            const short* rrow = wbase + (mt * 16 + n) * 64;
            #pragma unroll
            for (int kt = 0; kt < 2; ++kt) {
                const int gr = (kt * 8 + quad * 2) ^ ((n & 7) << 1);
                wa[mt][kt] = *(const short8*)(rrow + gr * 4);
            }
        }
        #pragma unroll
        for (int mt = 0; mt < 2; ++mt)
            #pragma unroll
            for (int kt = 0; kt < 2; ++kt)
                #pragma unroll
                for (int nt = 0; nt < 4; ++nt)
                    acc[mt][nt] = __builtin_amdgcn_mfma_f32_16x16x32_bf16(wa[mt][kt], vf[kt][nt], acc[mt][nt], 0, 0, 0);
    }

    // ---- epilogue ----
    lsum[0] += __shfl_xor(lsum[0], 16); lsum[0] += __shfl_xor(lsum[0], 32);
    lsum[1] += __shfl_xor(lsum[1], 16); lsum[1] += __shfl_xor(lsum[1], 32);
    if (quad == 0) {
        lb[ph * 32 + n]      = lsum[0];
        lb[ph * 32 + 16 + n] = lsum[1];
    }
    __syncthreads();   // everyone done with Wt; smem becomes Obuf
    #pragma unroll
    for (int mt = 0; mt < 2; ++mt)
        #pragma unroll
        for (int nt = 0; nt < 4; ++nt)
            #pragma unroll
            for (int r = 0; r < 4; ++r)
                Obuf[ph * 2112 + (mt * 16 + quad * 4 + r) * 66 + nt * 16 + n] = acc[mt][nt][r];
    __syncthreads();

    // merge 4 p-quarters, normalize, + ftr, store, emit stats partials
    const int c = tid >> 2, qq = tid & 3;
    const float dlt = delta[0];
    const size_t gbase = ((size_t)(b * 64 + c)) * PP + q0 + qq * 8;
    float4 f0 = *(const float4*)(ftr + gbase);
    float4 f1 = *(const float4*)(ftr + gbase + 4);
    float fr[8] = {f0.x, f0.y, f0.z, f0.w, f1.x, f1.y, f1.z, f1.w};
    float ov[8];
    float s8 = 0.f, m8 = -3.4e38f;
    #pragma unroll
    for (int i = 0; i < 8; ++i) {
        const int q = qq * 8 + i;
        float o = Obuf[q * 66 + c] + Obuf[2112 + q * 66 + c]
                + Obuf[4224 + q * 66 + c] + Obuf[6336 + q * 66 + c];
        float lq = lb[q] + lb[32 + q] + lb[64 + q] + lb[96 + q];
        float v = dlt * o / lq + fr[i];
        ov[i] = v; s8 += v; m8 = fmaxf(m8, v);
    }
    float4 o0 = {ov[0], ov[1], ov[2], ov[3]};
    float4 o1 = {ov[4], ov[5], ov[6], ov[7]};
    *(float4*)(out + gbase)     = o0;
    *(float4*)(out + gbase + 4) = o1;

    s8 += __shfl_xor(s8, 1); s8 += __shfl_xor(s8, 2);
    m8 = fmaxf(m8, __shfl_xor(m8, 1)); m8 = fmaxf(m8, __shfl_xor(m8, 2));
    if (qq == 0) {
        psum[((size_t)b * 128 + qblk) * 64 + c] = s8;
        pmax[((size_t)b * 128 + qblk) * 64 + c] = m8;
    }
}

// ---------------------------------------------------------------------------
// Kernel 3: reduce stats partials + SE MLP gate. grid = B blocks, 256 thr.
// ---------------------------------------------------------------------------
__global__ __launch_bounds__(256) void reduce_gate_kernel(
    const float* __restrict__ psum, const float* __restrict__ pmax,
    const float* __restrict__ w_avg1, const float* __restrict__ w_avg2,
    const float* __restrict__ w_max1, const float* __restrict__ w_max2,
    float* __restrict__ gate)
{
    const int b = blockIdx.x, t = threadIdx.x;
    const int c = t & 63, ch = t >> 6;
    float s = 0.f, m = -3.4e38f;
    for (int i = 0; i < 32; ++i) {
        const int part = ch * 32 + i;
        s += psum[((size_t)b * 128 + part) * 64 + c];
        m = fmaxf(m, pmax[((size_t)b * 128 + part) * 64 + c]);
    }
    __shared__ float ss[4][64], sm[4][64], fa[64], fm[64], ha[16], hm[16];
    ss[ch][c] = s; sm[ch][c] = m;
    __syncthreads();
    if (t < 64) {
        fa[t] = (ss[0][t] + ss[1][t] + ss[2][t] + ss[3][t]) * (1.f / 4096.f);
        fm[t] = fmaxf(fmaxf(sm[0][t], sm[1][t]), fmaxf(sm[2][t], sm[3][t]));
    }
    __syncthreads();
    if (t < 16) {
        float a = 0.f;
        for (int cc = 0; cc < 64; ++cc) a += fa[cc] * w_avg1[t * 64 + cc];
        ha[t] = fmaxf(a, 0.f);
    } else if (t < 32) {
        float a = 0.f;
        for (int cc = 0; cc < 64; ++cc) a += fm[cc] * w_max1[(t - 16) * 64 + cc];
        hm[t - 16] = fmaxf(a, 0.f);
    }
    __syncthreads();
    if (t < 64) {
        float a = 0.f, mm = 0.f;
        #pragma unroll
        for (int i = 0; i < 16; ++i) {
            a  += ha[i] * w_avg2[t * 16 + i];
            mm += hm[i] * w_max2[t * 16 + i];
        }
        gate[b * 64 + t] = 1.f / (1.f + expf(-(a + mm)));
    }
}

// ---------------------------------------------------------------------------
// Kernel 4: in-place gate multiply, float4. grid = 1024 blocks.
// ---------------------------------------------------------------------------
__global__ __launch_bounds__(256) void mul_kernel(
    float* __restrict__ out, const float* __restrict__ gate)
{
    const float g = gate[blockIdx.x >> 2];   // 4096 elements per (b,c) row
    const size_t e = ((size_t)blockIdx.x * 256 + threadIdx.x) * 4;
    float4 v = *(const float4*)(out + e);
    v.x *= g; v.y *= g; v.z *= g; v.w *= g;
    *(float4*)(out + e) = v;
}

// ---------------------------------------------------------------------------
extern "C" void kernel_launch(void* const* d_in, const int* in_sizes, int n_in,
                              void* d_out, int out_size, void* d_ws, size_t ws_size,
                              hipStream_t stream)
{
    const float* ftr    = (const float*)d_in[0];
    const float* wq     = (const float*)d_in[1];
    const float* bq     = (const float*)d_in[2];
    const float* wk     = (const float*)d_in[3];
    const float* bk     = (const float*)d_in[4];
    const float* wv     = (const float*)d_in[5];
    const float* bv     = (const float*)d_in[6];
    const float* delta  = (const float*)d_in[7];
    const float* w_avg1 = (const float*)d_in[8];
    const float* w_avg2 = (const float*)d_in[9];
    const float* w_max1 = (const float*)d_in[10];
    const float* w_max2 = (const float*)d_in[11];
    float* out = (float*)d_out;

    short* wsS  = (short*)d_ws;
    short* q16  = wsS;                 // 4*4096*16 = 262144 shorts (512 KB)
    short* k16  = wsS + 262144;        // 512 KB
    short* v_sw = wsS + 524288;        // 4*131072*2 = 2 MB
    float* fbase = (float*)(wsS + 1572864);
    float* psum = fbase;               // 4*128*64 = 32768 floats
    float* pmax = fbase + 32768;       // 32768 floats
    float* gate = fbase + 65536;       // 256 floats

    qkv_kernel<<<256, 256, 0, stream>>>(ftr, wq, bq, wk, bk, wv, bv, q16, k16, v_sw);
    attn_kernel<<<512, 256, 0, stream>>>(q16, k16, v_sw, ftr, delta, out, psum, pmax);
    reduce_gate_kernel<<<4, 256, 0, stream>>>(psum, pmax, w_avg1, w_avg2, w_max1, w_max2, gate);
    mul_kernel<<<1024, 256, 0, stream>>>(out, gate);
}